// Round 2
// baseline (1108.640 us; speedup 1.0000x reference)
//
#include <hip/hip_runtime.h>
#include <stdint.h>

#define E_EDGES 200000
#define D_FEAT  256
#define K1      1024     // 4*D
#define HID     512
#define DOUT    256
#define M_TILE  128
#define BK      64
#define NCHUNK  256

#define SA_PITCH 72      // 64 + 8 pad (keeps 16B align, 2-way banks)
#define SB_PITCH 72
#define SH_PITCH 264     // 256 + 8 pad

typedef short bf16x8 __attribute__((ext_vector_type(8)));
typedef float f32x4  __attribute__((ext_vector_type(4)));

__device__ __forceinline__ unsigned short f2bf(float x) {
    unsigned int u = __builtin_bit_cast(unsigned int, x);
    u += 0x7FFFu + ((u >> 16) & 1u);           // RNE
    return (unsigned short)(u >> 16);
}

// ---- prep: W1 [1024,512] -> w1t bf16 [512,1024]; W2 [512,256] -> w2t bf16 [256,512]
__global__ void prep_weights(const float* __restrict__ W1, const float* __restrict__ W2,
                             unsigned short* __restrict__ w1t, unsigned short* __restrict__ w2t) {
    int idx = blockIdx.x * 256 + threadIdx.x;
    if (idx < HID * K1) {
        int n = idx >> 10;          // 0..511  (HID)
        int k = idx & 1023;         // 0..1023 (K1)
        w1t[idx] = f2bf(W1[k * HID + n]);
    } else if (idx < HID * K1 + DOUT * HID) {
        int j = idx - HID * K1;
        int n = j >> 9;             // 0..255 (DOUT)
        int k = j & 511;            // 0..511 (HID)
        w2t[j] = f2bf(W2[k * DOUT + n]);
    }
}

__launch_bounds__(512, 2)
__global__ void edge_mlp_kernel(const float* __restrict__ src,
                                const float* __restrict__ dst,
                                const float* __restrict__ ea,
                                const float* __restrict__ u,
                                const int*   __restrict__ batch,
                                const float* __restrict__ b1,
                                const float* __restrict__ b2,
                                const unsigned short* __restrict__ w1t,
                                const unsigned short* __restrict__ w2t,
                                float* __restrict__ out) {
    __shared__ unsigned short sA[M_TILE * SA_PITCH];   // 18432 B
    __shared__ unsigned short sB[NCHUNK * SB_PITCH];   // 36864 B
    __shared__ unsigned short sH[M_TILE * SH_PITCH];   // 67584 B
    __shared__ int sBatch[M_TILE];

    const int tid  = threadIdx.x;
    const int lane = tid & 63;
    const int wave = tid >> 6;                 // 0..7
    const int rw   = (wave >> 2) * 64;         // 0 or 64 (row group)
    const int cw   = (wave & 3) * 64;          // 0/64/128/192 (col group)
    const int lrow = lane & 15;
    const int quad = lane >> 4;
    const int e0   = blockIdx.x * M_TILE;

    if (tid < M_TILE) {
        int e = e0 + tid;
        if (e >= E_EDGES) e = E_EDGES - 1;
        sBatch[tid] = batch[e];
    }

    const f32x4 z4 = {0.f, 0.f, 0.f, 0.f};
    f32x4 oacc[4][4];
#pragma unroll
    for (int i = 0; i < 4; ++i)
#pragma unroll
        for (int j = 0; j < 4; ++j) oacc[i][j] = z4;

    // staging coords (loop-invariant)
    const int ar = tid >> 2;                   // X row 0..127
    const int acq = (tid & 3) << 4;            // X col offset 0/16/32/48
    const int bn = tid >> 1;                   // W row 0..255
    const int bkq = (tid & 1) << 5;            // W col offset 0/32

    for (int c = 0; c < 2; ++c) {
        const int nb = c * NCHUNK;             // H-column base of this chunk
        f32x4 hacc[4][4];
#pragma unroll
        for (int i = 0; i < 4; ++i)
#pragma unroll
            for (int j = 0; j < 4; ++j) hacc[i][j] = z4;

        // ---- layer-1 K loop ----
        for (int k0 = 0; k0 < K1; k0 += BK) {
            __syncthreads();
            // stage X tile [128 x 64] (gathered, fp32 -> bf16)
            {
                int e = e0 + ar; if (e >= E_EDGES) e = E_EDGES - 1;
                const int seg = k0 >> 8;
                const int ko  = (k0 & 255) + acq;
                const float* base;
                if      (seg == 0) base = src + (size_t)e * D_FEAT;
                else if (seg == 1) base = dst + (size_t)e * D_FEAT;
                else if (seg == 2) base = ea  + (size_t)e * D_FEAT;
                else               base = u   + (size_t)sBatch[ar] * D_FEAT;
                const float4* p = reinterpret_cast<const float4*>(base + ko);
                float4 f0 = p[0], f1 = p[1], f2v = p[2], f3 = p[3];
                unsigned int w0 = (unsigned)f2bf(f0.x)  | ((unsigned)f2bf(f0.y)  << 16);
                unsigned int w1 = (unsigned)f2bf(f0.z)  | ((unsigned)f2bf(f0.w)  << 16);
                unsigned int w2 = (unsigned)f2bf(f1.x)  | ((unsigned)f2bf(f1.y)  << 16);
                unsigned int w3 = (unsigned)f2bf(f1.z)  | ((unsigned)f2bf(f1.w)  << 16);
                unsigned int w4 = (unsigned)f2bf(f2v.x) | ((unsigned)f2bf(f2v.y) << 16);
                unsigned int w5 = (unsigned)f2bf(f2v.z) | ((unsigned)f2bf(f2v.w) << 16);
                unsigned int w6 = (unsigned)f2bf(f3.x)  | ((unsigned)f2bf(f3.y)  << 16);
                unsigned int w7 = (unsigned)f2bf(f3.z)  | ((unsigned)f2bf(f3.w)  << 16);
                uint4* dsp = reinterpret_cast<uint4*>(&sA[ar * SA_PITCH + acq]);
                dsp[0] = make_uint4(w0, w1, w2, w3);
                dsp[1] = make_uint4(w4, w5, w6, w7);
            }
            // stage W1^T tile [256 x 64] bf16
            {
                const uint4* p = reinterpret_cast<const uint4*>(w1t + (size_t)(nb + bn) * K1 + k0 + bkq);
                uint4 q0 = p[0], q1 = p[1], q2 = p[2], q3 = p[3];
                uint4* dsp = reinterpret_cast<uint4*>(&sB[bn * SB_PITCH + bkq]);
                dsp[0] = q0; dsp[1] = q1; dsp[2] = q2; dsp[3] = q3;
            }
            __syncthreads();
#pragma unroll
            for (int kk = 0; kk < BK; kk += 32) {
                bf16x8 af[4], bfr[4];
#pragma unroll
                for (int i = 0; i < 4; ++i)
                    af[i] = *reinterpret_cast<const bf16x8*>(&sA[(rw + i * 16 + lrow) * SA_PITCH + kk + quad * 8]);
#pragma unroll
                for (int j = 0; j < 4; ++j)
                    bfr[j] = *reinterpret_cast<const bf16x8*>(&sB[(cw + j * 16 + lrow) * SB_PITCH + kk + quad * 8]);
#pragma unroll
                for (int i = 0; i < 4; ++i)
#pragma unroll
                    for (int j = 0; j < 4; ++j)
                        hacc[i][j] = __builtin_amdgcn_mfma_f32_16x16x32_bf16(af[i], bfr[j], hacc[i][j], 0, 0, 0);
            }
        }

        // ---- epilogue layer 1: bias + relu -> sH (bf16) ----
        __syncthreads();
#pragma unroll
        for (int j = 0; j < 4; ++j) {
            const int col = cw + j * 16 + lrow;
            const float bb = b1[nb + col];
#pragma unroll
            for (int i = 0; i < 4; ++i) {
#pragma unroll
                for (int r = 0; r < 4; ++r) {
                    int row = rw + i * 16 + quad * 4 + r;
                    float v = hacc[i][j][r] + bb;
                    v = fmaxf(v, 0.f);
                    sH[row * SH_PITCH + col] = f2bf(v);
                }
            }
        }
        __syncthreads();

        // ---- layer-2: oacc += sH[128 x 256] @ W2^T-chunk ----
        for (int k20 = 0; k20 < NCHUNK; k20 += BK) {
            __syncthreads();
            {
                const uint4* p = reinterpret_cast<const uint4*>(w2t + (size_t)bn * HID + nb + k20 + bkq);
                uint4 q0 = p[0], q1 = p[1], q2 = p[2], q3 = p[3];
                uint4* dsp = reinterpret_cast<uint4*>(&sB[bn * SB_PITCH + bkq]);
                dsp[0] = q0; dsp[1] = q1; dsp[2] = q2; dsp[3] = q3;
            }
            __syncthreads();
#pragma unroll
            for (int kk = 0; kk < BK; kk += 32) {
                bf16x8 af[4], bfr[4];
#pragma unroll
                for (int i = 0; i < 4; ++i)
                    af[i] = *reinterpret_cast<const bf16x8*>(&sH[(rw + i * 16 + lrow) * SH_PITCH + k20 + kk + quad * 8]);
#pragma unroll
                for (int j = 0; j < 4; ++j)
                    bfr[j] = *reinterpret_cast<const bf16x8*>(&sB[(cw + j * 16 + lrow) * SB_PITCH + kk + quad * 8]);
#pragma unroll
                for (int i = 0; i < 4; ++i)
#pragma unroll
                    for (int j = 0; j < 4; ++j)
                        oacc[i][j] = __builtin_amdgcn_mfma_f32_16x16x32_bf16(af[i], bfr[j], oacc[i][j], 0, 0, 0);
            }
        }
    }

    // ---- final epilogue: + b2, store fp32 ----
#pragma unroll
    for (int j = 0; j < 4; ++j) {
        const int col = cw + j * 16 + lrow;
        const float bb = b2[col];
#pragma unroll
        for (int i = 0; i < 4; ++i) {
            const int rbase = rw + i * 16 + quad * 4;
#pragma unroll
            for (int r = 0; r < 4; ++r) {
                int e = e0 + rbase + r;
                if (e < E_EDGES)
                    out[(size_t)e * DOUT + col] = oacc[i][j][r] + bb;
            }
        }
    }
}

extern "C" void kernel_launch(void* const* d_in, const int* in_sizes, int n_in,
                              void* d_out, int out_size, void* d_ws, size_t ws_size,
                              hipStream_t stream) {
    (void)in_sizes; (void)n_in; (void)out_size; (void)ws_size;
    const float* src  = (const float*)d_in[0];
    const float* dst  = (const float*)d_in[1];
    const float* ea   = (const float*)d_in[2];
    const float* u    = (const float*)d_in[3];
    const int*   bat  = (const int*)d_in[4];
    const float* W1   = (const float*)d_in[5];
    const float* b1   = (const float*)d_in[6];
    const float* W2   = (const float*)d_in[7];
    const float* b2   = (const float*)d_in[8];
    float* out = (float*)d_out;

    unsigned short* w1t = (unsigned short*)d_ws;             // 512*1024 bf16 = 1 MiB
    unsigned short* w2t = w1t + (size_t)HID * K1;            // 256*512  bf16 = 256 KiB

    prep_weights<<<(HID * K1 + DOUT * HID) / 256, 256, 0, stream>>>(W1, W2, w1t, w2t);

    const int nblocks = (E_EDGES + M_TILE - 1) / M_TILE;     // 1563
    edge_mlp_kernel<<<nblocks, 512, 0, stream>>>(src, dst, ea, u, bat, b1, b2, w1t, w2t, out);
}